// Round 1
// baseline (456.266 us; speedup 1.0000x reference)
//
#include <hip/hip_runtime.h>

#define IN_K 1024
#define OUT_N 1024

typedef short v8s __attribute__((ext_vector_type(8)));
typedef float v4f __attribute__((ext_vector_type(4)));

__device__ __forceinline__ unsigned int bf16_rne(float f) {
    unsigned int u = __float_as_uint(f);
    u += 0x7FFFu + ((u >> 16) & 1u);
    return u >> 16;
}

// ---------------- Kernel 1a: per-column stats ----------------
// colinv[j] = 1/max(||wv[:,j]||, 1e-15); coshd/sinhd of drcr=2*rc*bias; gfac=2*g
__global__ void prep_cols(const float* __restrict__ wv, const float* __restrict__ wg,
                          const float* __restrict__ bias, const float* __restrict__ cptr,
                          float* __restrict__ colinv, float* __restrict__ coshd,
                          float* __restrict__ sinhd, float* __restrict__ gfac) {
    __shared__ float red[4][64];
    const int t = threadIdx.x;
    const int cj = t & 63, rr = t >> 6;
    const int col = blockIdx.x * 64 + cj;
    float ss = 0.f;
    for (int i = 0; i < 256; ++i) {
        float v = wv[(size_t)(rr * 256 + i) * OUT_N + col];
        ss = fmaf(v, v, ss);
    }
    red[rr][cj] = ss;
    __syncthreads();
    if (rr == 0) {
        ss = red[0][cj] + red[1][cj] + red[2][cj] + red[3][cj];
        colinv[col] = 1.0f / fmaxf(sqrtf(ss), 1e-15f);
        float c = cptr[0];
        float rc = sqrtf(c);
        float d = 2.0f * rc * bias[col];
        float e = __expf(d);
        float ie = 1.0f / e;
        coshd[col] = 0.5f * (e + ie);
        sinhd[col] = 0.5f * (e - ie);
        gfac[col] = 2.0f * wg[col];
    }
}

// ---------------- Kernel 1b: Bt[n][k] = bf16(wv[k][n] * colinv[n]) ----------------
__global__ void build_bt(const float* __restrict__ wv, const float* __restrict__ colinv,
                         unsigned short* __restrict__ Bt) {
    __shared__ float tile[64 * 65];
    const int t = threadIdx.x;
    const int ti = blockIdx.x & 15;   // k tile
    const int tj = blockIdx.x >> 4;   // n tile
    {
        const int kl = t >> 2;        // 0..63 row (k) within tile
        const int cc = t & 3;         // 16 cols each
        const float* src = wv + (size_t)(ti * 64 + kl) * OUT_N + tj * 64 + cc * 16;
        float4 fq[4];
#pragma unroll
        for (int i = 0; i < 4; ++i) fq[i] = ((const float4*)src)[i];
        float* dst = &tile[kl * 65 + cc * 16];
#pragma unroll
        for (int i = 0; i < 4; ++i) {
            dst[4 * i + 0] = fq[i].x; dst[4 * i + 1] = fq[i].y;
            dst[4 * i + 2] = fq[i].z; dst[4 * i + 3] = fq[i].w;
        }
    }
    __syncthreads();
    {
        const int nl = t & 63, kc = t >> 6;
        const int n = tj * 64 + nl;
        const float ci = colinv[n];
        unsigned int p[8];
#pragma unroll
        for (int j = 0; j < 8; ++j) {
            float v0 = tile[(kc * 16 + 2 * j) * 65 + nl] * ci;
            float v1 = tile[(kc * 16 + 2 * j + 1) * 65 + nl] * ci;
            p[j] = bf16_rne(v0) | (bf16_rne(v1) << 16);
        }
        unsigned short* dst = Bt + (size_t)n * IN_K + ti * 64 + kc * 16;
        *(uint4*)(dst) = make_uint4(p[0], p[1], p[2], p[3]);
        *(uint4*)(dst + 8) = make_uint4(p[4], p[5], p[6], p[7]);
    }
}

// ---------------- Main kernel: 64 rows/block, full OUT per block ----------------
// 8 waves; wave w owns all 64 rows x cols [w*128, w*128+128).
// A staged fp32->bf16 into LDS in MFMA fragment order, K in 4 quarters of 256.
__launch_bounds__(512, 2)
__global__ void poincare_main(const float* __restrict__ x,
                              const unsigned short* __restrict__ Bt,
                              const float* __restrict__ cptr,
                              const float* __restrict__ coshd,
                              const float* __restrict__ sinhd,
                              const float* __restrict__ gfac,
                              float* __restrict__ out, int N) {
    __shared__ __align__(16) unsigned short Alds[32 * 512]; // 32 frag-blocks x 64 lanes x 8 bf16 = 32 KB
    __shared__ float s_cx2[64];
    __shared__ float s_sum[64];
    __shared__ float s_f[64];

    const int t = threadIdx.x;
    const int w = t >> 6;       // wave 0..7
    const int L = t & 63;
    const int lm = L & 15;
    const int q  = L >> 4;      // 0..3
    const int r0 = blockIdx.x * 64;

    const float cc = cptr[0];
    const float rc = sqrtf(cc);

    if (t < 64) { s_cx2[t] = 0.f; s_sum[t] = 0.f; }

    v4f acc[4][8];
#pragma unroll
    for (int mt = 0; mt < 4; ++mt)
#pragma unroll
        for (int nt = 0; nt < 8; ++nt) acc[mt][nt] = (v4f){0.f, 0.f, 0.f, 0.f};

    const int mtw = w & 3;      // staging row-tile of this wave
    const int par = w >> 2;     // staging ks parity
    const int xrow = r0 + mtw * 16 + lm;
    const bool rowok = (xrow < N);
    const float* xrp = x + (size_t)xrow * IN_K;
    float xpart = 0.f;

    for (int kq = 0; kq < 4; ++kq) {
        // ---- stage quarter: rows 0..63, k in [kq*256, kq*256+256) ----
#pragma unroll
        for (int i = 0; i < 4; ++i) {
            const int ksl = i * 2 + par;                  // 0..7
            const int kg = kq * 256 + ksl * 32 + q * 8;
            float4 f0 = make_float4(0.f, 0.f, 0.f, 0.f);
            float4 f1 = make_float4(0.f, 0.f, 0.f, 0.f);
            if (rowok) {
                f0 = *(const float4*)(xrp + kg);
                f1 = *(const float4*)(xrp + kg + 4);
            }
            float vals[8] = {f0.x, f0.y, f0.z, f0.w, f1.x, f1.y, f1.z, f1.w};
            unsigned int pk[4];
#pragma unroll
            for (int j = 0; j < 4; ++j) {
                xpart = fmaf(vals[2 * j], vals[2 * j], xpart);
                xpart = fmaf(vals[2 * j + 1], vals[2 * j + 1], xpart);
                pk[j] = bf16_rne(vals[2 * j]) | (bf16_rne(vals[2 * j + 1]) << 16);
            }
            *(uint4*)&Alds[(ksl * 4 + mtw) * 512 + L * 8] = make_uint4(pk[0], pk[1], pk[2], pk[3]);
        }
        __syncthreads();
        // ---- compute: 8 k-steps of 32 ----
#pragma unroll
        for (int ksl = 0; ksl < 8; ++ksl) {
            const int kg = kq * 256 + ksl * 32 + q * 8;
            v8s a0 = *(const v8s*)&Alds[(ksl * 4 + 0) * 512 + L * 8];
            v8s a1 = *(const v8s*)&Alds[(ksl * 4 + 1) * 512 + L * 8];
            v8s a2 = *(const v8s*)&Alds[(ksl * 4 + 2) * 512 + L * 8];
            v8s a3 = *(const v8s*)&Alds[(ksl * 4 + 3) * 512 + L * 8];
#pragma unroll
            for (int nt = 0; nt < 8; ++nt) {
                const int n = w * 128 + nt * 16 + lm;
                v8s b = *(const v8s*)(Bt + (size_t)n * IN_K + kg);
                acc[0][nt] = __builtin_amdgcn_mfma_f32_16x16x32_bf16(a0, b, acc[0][nt], 0, 0, 0);
                acc[1][nt] = __builtin_amdgcn_mfma_f32_16x16x32_bf16(a1, b, acc[1][nt], 0, 0, 0);
                acc[2][nt] = __builtin_amdgcn_mfma_f32_16x16x32_bf16(a2, b, acc[2][nt], 0, 0, 0);
                acc[3][nt] = __builtin_amdgcn_mfma_f32_16x16x32_bf16(a3, b, acc[3][nt], 0, 0, 0);
            }
        }
        __syncthreads();
    }

    // ---- row Sum(x^2): 8 lane-partials per row ----
    atomicAdd(&s_cx2[mtw * 16 + lm], xpart);
    __syncthreads();

    // ---- fused nonlinear epilogue ----
    float ch[8], sh[8], gf[8];
#pragma unroll
    for (int nt = 0; nt < 8; ++nt) {
        const int n = w * 128 + nt * 16 + lm;
        ch[nt] = coshd[n]; sh[nt] = sinhd[n]; gf[nt] = gfac[n];
    }
    const float halfinvrc = 0.5f / rc;
    const float two_rc = 2.0f * rc;
    float rs[4][4];
#pragma unroll
    for (int mt = 0; mt < 4; ++mt)
#pragma unroll
        for (int rr = 0; rr < 4; ++rr) rs[mt][rr] = 0.f;

#pragma unroll
    for (int mt = 0; mt < 4; ++mt) {
        float sx[4];
#pragma unroll
        for (int rr = 0; rr < 4; ++rr) sx[rr] = s_cx2[mt * 16 + q * 4 + rr];
#pragma unroll
        for (int nt = 0; nt < 8; ++nt) {
            v4f d = acc[mt][nt];
#pragma unroll
            for (int rr = 0; rr < 4; ++rr) {
                float dot = d[rr];
                float cx2 = cc * sx[rr];
                float num = two_rc * dot * ch[nt] - (1.0f + cx2) * sh[nt];
                float den = fmaxf(1.0f - cx2, 1e-15f);
                float tt = num * __builtin_amdgcn_rcpf(den);
                float as_ = __logf(fabsf(tt) + sqrtf(fmaf(tt, tt, 1.0f)));
                as_ = copysignf(as_, tt);
                float u = gf[nt] * as_;                 // u = rc*mlr = 2*g*asinh(...)
                float e = __expf(u);
                float y = (e - __builtin_amdgcn_rcpf(e)) * halfinvrc;  // sinh(u)/rc
                d[rr] = y;
                rs[mt][rr] = fmaf(y, y, rs[mt][rr]);
            }
            acc[mt][nt] = d;
        }
    }
    // reduce Sum(y^2) across the 16 lanes of each quad-row group, then across waves
#pragma unroll
    for (int mt = 0; mt < 4; ++mt)
#pragma unroll
        for (int rr = 0; rr < 4; ++rr) {
            float v = rs[mt][rr];
            v += __shfl_xor(v, 1); v += __shfl_xor(v, 2);
            v += __shfl_xor(v, 4); v += __shfl_xor(v, 8);
            if (lm == 0) atomicAdd(&s_sum[mt * 16 + q * 4 + rr], v);
        }
    __syncthreads();
    if (t < 64) {
        float s = s_sum[t];
        float scale = 1.0f / (1.0f + sqrtf(fmaf(cc, s, 1.0f)));  // gyro half-map
        float nrm = fmaxf(sqrtf(s) * scale, 1e-15f);             // ||y_post||
        float mn = (cc > 0.f) ? 0.996f / sqrtf(fmaxf(cc, 1e-15f)) : 1e15f;
        s_f[t] = scale * (nrm > mn ? mn / nrm : 1.0f);
    }
    __syncthreads();

    // ---- store ----
#pragma unroll
    for (int mt = 0; mt < 4; ++mt) {
#pragma unroll
        for (int rr = 0; rr < 4; ++rr) {
            const int rl = mt * 16 + q * 4 + rr;
            const int row = r0 + rl;
            if (row < N) {
                const float f = s_f[rl];
                float* op = out + (size_t)row * OUT_N + w * 128 + lm;
#pragma unroll
                for (int nt = 0; nt < 8; ++nt) op[nt * 16] = acc[mt][nt][rr] * f;
            }
        }
    }
}

extern "C" void kernel_launch(void* const* d_in, const int* in_sizes, int n_in,
                              void* d_out, int out_size, void* d_ws, size_t ws_size,
                              hipStream_t stream) {
    const float* x    = (const float*)d_in[0];
    const float* wv   = (const float*)d_in[1];
    const float* wg   = (const float*)d_in[2];
    const float* bias = (const float*)d_in[3];
    const float* cptr = (const float*)d_in[4];
    float* out = (float*)d_out;

    const int OUT = in_sizes[2];            // 1024
    const int IN  = in_sizes[1] / OUT;      // 1024
    const int N   = in_sizes[0] / IN;       // 32768

    float* colinv = (float*)d_ws;
    float* coshd  = colinv + OUT;
    float* sinhd  = coshd + OUT;
    float* gfac   = sinhd + OUT;
    unsigned short* Bt = (unsigned short*)(gfac + OUT);   // [OUT][IN] bf16, 2 MB

    prep_cols<<<OUT / 64, 256, 0, stream>>>(wv, wg, bias, cptr, colinv, coshd, sinhd, gfac);
    build_bt<<<(IN / 64) * (OUT / 64), 256, 0, stream>>>(wv, colinv, Bt);
    poincare_main<<<(N + 63) / 64, 512, 0, stream>>>(x, Bt, cptr, coshd, sinhd, gfac, out, N);
}

// Round 2
// 426.621 us; speedup vs baseline: 1.0695x; 1.0695x over previous
//
#include <hip/hip_runtime.h>

#define K_DIM 1024
#define N_DIM 1024

typedef short v8s __attribute__((ext_vector_type(8)));
typedef float v4f __attribute__((ext_vector_type(4)));

__device__ __forceinline__ unsigned int bf16_rne(float f) {
    unsigned int u = __float_as_uint(f);
    u += 0x7FFFu + ((u >> 16) & 1u);
    return u >> 16;
}

// ---------- colss[n] += partial sum of wv[:,n]^2  (128 blocks) ----------
__global__ void sumsq_cols(const float* __restrict__ wv, float* __restrict__ colss) {
    __shared__ float red[4][64];
    const int t = threadIdx.x;
    const int cj = t & 63, rr = t >> 6;
    const int col = (blockIdx.x & 15) * 64 + cj;
    const int k0 = (blockIdx.x >> 4) * 128 + rr * 32;
    float ss = 0.f;
#pragma unroll 8
    for (int i = 0; i < 32; ++i) {
        float v = wv[(size_t)(k0 + i) * N_DIM + col];
        ss = fmaf(v, v, ss);
    }
    red[rr][cj] = ss;
    __syncthreads();
    if (rr == 0) atomicAdd(&colss[col], red[0][cj] + red[1][cj] + red[2][cj] + red[3][cj]);
}

// ---------- per-column constants ----------
__global__ void finalize_cols(const float* __restrict__ colss, const float* __restrict__ wg,
                              const float* __restrict__ bias, const float* __restrict__ cptr,
                              float* __restrict__ colinv, float* __restrict__ coshd,
                              float* __restrict__ sinhd, float* __restrict__ gfac) {
    const int col = blockIdx.x * 256 + threadIdx.x;
    const float rc = sqrtf(cptr[0]);
    colinv[col] = 1.0f / fmaxf(sqrtf(colss[col]), 1e-15f);
    float d = 2.0f * rc * bias[col];
    float e = __expf(d), ie = 1.0f / e;
    coshd[col] = 0.5f * (e + ie);
    sinhd[col] = 0.5f * (e - ie);
    gfac[col] = 2.0f * wg[col];
}

// ---------- Btf: z_unit^T in MFMA B-fragment order ----------
// element (n,k) -> flat (((n>>4)*32 + (k>>5))*64 + ((n&15) | (((k>>3)&3)<<4)))*8 + (k&7)
__global__ void build_bt(const float* __restrict__ wv, const float* __restrict__ colinv,
                         unsigned short* __restrict__ Btf) {
    __shared__ float tile[64 * 65];
    const int t = threadIdx.x;
    const int ti = blockIdx.x & 15;   // k tile of 64
    const int tj = blockIdx.x >> 4;   // n tile of 64
    {
        const int kl = t >> 2;        // k row within tile
        const int cc = t & 3;
        const float* src = wv + (size_t)(ti * 64 + kl) * N_DIM + tj * 64 + cc * 16;
        float4 fq[4];
#pragma unroll
        for (int i = 0; i < 4; ++i) fq[i] = ((const float4*)src)[i];
        float* dst = &tile[kl * 65 + cc * 16];
#pragma unroll
        for (int i = 0; i < 4; ++i) {
            dst[4 * i + 0] = fq[i].x; dst[4 * i + 1] = fq[i].y;
            dst[4 * i + 2] = fq[i].z; dst[4 * i + 3] = fq[i].w;
        }
    }
    __syncthreads();
    {
        const int nl = t & 63, kc = t >> 6;
        const int n = tj * 64 + nl;
        const float ci = colinv[n];
        const int nt_g = tj * 4 + (nl >> 4);
#pragma unroll
        for (int h = 0; h < 2; ++h) {
            const int k8g = ti * 8 + kc * 2 + h;
            const int ks_g = k8g >> 2;
            const int L = (nl & 15) | ((k8g & 3) << 4);
            unsigned int p[4];
#pragma unroll
            for (int j = 0; j < 4; ++j) {
                float v0 = tile[(kc * 16 + h * 8 + 2 * j) * 65 + nl] * ci;
                float v1 = tile[(kc * 16 + h * 8 + 2 * j + 1) * 65 + nl] * ci;
                p[j] = bf16_rne(v0) | (bf16_rne(v1) << 16);
            }
            *(uint4*)(Btf + ((size_t)(nt_g * 32 + ks_g) * 64 + L) * 8) =
                make_uint4(p[0], p[1], p[2], p[3]);
        }
    }
}

// ---------- GEMM 128x128 + fused transcendental epilogue ----------
// writes unscaled y to out, per-row Sum(y^2) partials to rowsum (atomic)
__launch_bounds__(256, 3)
__global__ void gemm_phase(const float* __restrict__ x, const unsigned short* __restrict__ Btf,
                           const float* __restrict__ cptr, const float* __restrict__ coshd,
                           const float* __restrict__ sinhd, const float* __restrict__ gfac,
                           float* __restrict__ out, float* __restrict__ rowsum) {
    __shared__ __align__(16) unsigned short As[16 * 512];  // 16 KB, frag order
    __shared__ __align__(16) unsigned short Bs[16 * 512];  // 16 KB, frag order
    __shared__ float s_cx2[128];
    __shared__ float s_rsum[128];

    const int t = threadIdx.x;
    const int w = t >> 6, L = t & 63;
    const int lm = L & 15, q = L >> 4;
    const int bn = blockIdx.x & 7;
    const int bm = blockIdx.x >> 3;
    const int r0 = bm * 128;

    if (t < 128) { s_cx2[t] = 0.f; s_rsum[t] = 0.f; }

    v4f acc[16];
#pragma unroll
    for (int i = 0; i < 16; ++i) acc[i] = (v4f){0.f, 0.f, 0.f, 0.f};

    const int smt0 = w * 2;                       // this wave stages m/n-tiles 2w, 2w+1
    const float* xr0 = x + (size_t)(r0 + smt0 * 16 + lm) * K_DIM;
    const float* xr1 = xr0 + (size_t)16 * K_DIM;
    float xp0 = 0.f, xp1 = 0.f;
    const int wm = w & 1, wn = w >> 1;

    for (int kq = 0; kq < 16; ++kq) {
        const int kbase = kq * 64;
        // B tile: 4 async frag-block loads per wave (contiguous 1 KB each)
#pragma unroll
        for (int i = 0; i < 4; ++i) {
            const int nt = smt0 + (i & 1);
            const int ks = i >> 1;
            const unsigned short* gp =
                Btf + ((size_t)((bn * 8 + nt) * 32 + (kq * 2 + ks)) * 64 + L) * 8;
            __builtin_amdgcn_global_load_lds(
                (const __attribute__((address_space(1))) unsigned int*)gp,
                (__attribute__((address_space(3))) unsigned int*)&Bs[(nt * 2 + ks) * 512],
                16, 0, 0);
        }
        // A tile: fp32 load + x^2 accumulate + bf16 pack + LDS write (frag order)
#pragma unroll
        for (int i = 0; i < 4; ++i) {
            const int half = i & 1;
            const int ks = i >> 1;
            const float* xr = half ? xr1 : xr0;
            const int kg = kbase + ks * 32 + q * 8;
            float4 f0 = *(const float4*)(xr + kg);
            float4 f1 = *(const float4*)(xr + kg + 4);
            float vals[8] = {f0.x, f0.y, f0.z, f0.w, f1.x, f1.y, f1.z, f1.w};
            unsigned int pk[4];
            float ssl = 0.f;
#pragma unroll
            for (int j = 0; j < 4; ++j) {
                ssl = fmaf(vals[2 * j], vals[2 * j], ssl);
                ssl = fmaf(vals[2 * j + 1], vals[2 * j + 1], ssl);
                pk[j] = bf16_rne(vals[2 * j]) | (bf16_rne(vals[2 * j + 1]) << 16);
            }
            if (half) xp1 += ssl; else xp0 += ssl;
            *(uint4*)&As[((smt0 + half) * 2 + ks) * 512 + L * 8] =
                make_uint4(pk[0], pk[1], pk[2], pk[3]);
        }
        __syncthreads();
#pragma unroll
        for (int ks = 0; ks < 2; ++ks) {
            v8s a[4], b[4];
#pragma unroll
            for (int mi = 0; mi < 4; ++mi)
                a[mi] = *(const v8s*)&As[((wm * 4 + mi) * 2 + ks) * 512 + L * 8];
#pragma unroll
            for (int ni = 0; ni < 4; ++ni)
                b[ni] = *(const v8s*)&Bs[((wn * 4 + ni) * 2 + ks) * 512 + L * 8];
#pragma unroll
            for (int mi = 0; mi < 4; ++mi)
#pragma unroll
                for (int ni = 0; ni < 4; ++ni)
                    acc[mi * 4 + ni] = __builtin_amdgcn_mfma_f32_16x16x32_bf16(
                        a[mi], b[ni], acc[mi * 4 + ni], 0, 0, 0);
        }
        __syncthreads();
    }

    // block-local cx2 (full K was staged by this block)
    atomicAdd(&s_cx2[smt0 * 16 + lm], xp0);
    atomicAdd(&s_cx2[smt0 * 16 + 16 + lm], xp1);
    __syncthreads();

    const float cc = cptr[0];
    const float rc = sqrtf(cc);
    const float two_rc = 2.0f * rc;
    const float halfinvrc = 0.5f / rc;
    float ch[4], sh[4], gf[4];
#pragma unroll
    for (int ni = 0; ni < 4; ++ni) {
        const int n = bn * 128 + wn * 64 + ni * 16 + lm;
        ch[ni] = coshd[n]; sh[ni] = sinhd[n]; gf[ni] = gfac[n];
    }
#pragma unroll
    for (int mi = 0; mi < 4; ++mi) {
        const int mloc = wm * 64 + mi * 16 + q * 4;
        float sx[4];
#pragma unroll
        for (int rr = 0; rr < 4; ++rr) sx[rr] = cc * s_cx2[mloc + rr];
        float rs[4] = {0.f, 0.f, 0.f, 0.f};
#pragma unroll
        for (int ni = 0; ni < 4; ++ni) {
            v4f d = acc[mi * 4 + ni];
#pragma unroll
            for (int rr = 0; rr < 4; ++rr) {
                float cx2 = sx[rr];
                float num = two_rc * d[rr] * ch[ni] - (1.0f + cx2) * sh[ni];
                float den = fmaxf(1.0f - cx2, 1e-15f);
                float tt = num * __builtin_amdgcn_rcpf(den);
                float as_ = __logf(fabsf(tt) + sqrtf(fmaf(tt, tt, 1.0f)));
                as_ = copysignf(as_, tt);
                float u = gf[ni] * as_;
                float e = __expf(u);
                float y = (e - __builtin_amdgcn_rcpf(e)) * halfinvrc;
                d[rr] = y;
                rs[rr] = fmaf(y, y, rs[rr]);
            }
            acc[mi * 4 + ni] = d;
        }
#pragma unroll
        for (int rr = 0; rr < 4; ++rr) {
            float v = rs[rr];
            v += __shfl_xor(v, 1); v += __shfl_xor(v, 2);
            v += __shfl_xor(v, 4); v += __shfl_xor(v, 8);
            if (lm == 0) atomicAdd(&s_rsum[mloc + rr], v);
        }
#pragma unroll
        for (int rr = 0; rr < 4; ++rr) {
            const int row = r0 + mloc + rr;
            float* op = out + (size_t)row * N_DIM + bn * 128 + wn * 64 + lm;
#pragma unroll
            for (int ni = 0; ni < 4; ++ni) op[ni * 16] = acc[mi * 4 + ni][rr];
        }
    }
    __syncthreads();
    if (t < 128) atomicAdd(&rowsum[r0 + t], s_rsum[t]);
}

// ---------- in-place row rescale ----------
__global__ void rescale(float* __restrict__ out, const float* __restrict__ rowsum,
                        const float* __restrict__ cptr) {
    const int row = blockIdx.x;
    const float cc = cptr[0];
    const float s = rowsum[row];
    const float scale = 1.0f / (1.0f + sqrtf(fmaf(cc, s, 1.0f)));
    const float nrm = fmaxf(sqrtf(s) * scale, 1e-15f);
    const float mn = (cc > 0.f) ? 0.996f / sqrtf(fmaxf(cc, 1e-15f)) : 1e15f;
    const float f = scale * (nrm > mn ? mn / nrm : 1.0f);
    float4* p = (float4*)(out + (size_t)row * N_DIM) + threadIdx.x;
    float4 v = *p;
    v.x *= f; v.y *= f; v.z *= f; v.w *= f;
    *p = v;
}

extern "C" void kernel_launch(void* const* d_in, const int* in_sizes, int n_in,
                              void* d_out, int out_size, void* d_ws, size_t ws_size,
                              hipStream_t stream) {
    const float* x    = (const float*)d_in[0];
    const float* wv   = (const float*)d_in[1];
    const float* wg   = (const float*)d_in[2];
    const float* bias = (const float*)d_in[3];
    const float* cptr = (const float*)d_in[4];
    float* out = (float*)d_out;

    const int OUT = in_sizes[2];            // 1024
    const int IN  = in_sizes[1] / OUT;      // 1024
    const int M   = in_sizes[0] / IN;       // 32768

    // ws layout: colss[1024] | rowsum[M] | colinv[1024] | coshd[1024] | sinhd[1024] | gfac[1024] | Btf[1M bf16]
    float* colss  = (float*)d_ws;
    float* rowsum = colss + 1024;
    float* colinv = rowsum + M;
    float* coshd  = colinv + 1024;
    float* sinhd  = coshd + 1024;
    float* gfac   = sinhd + 1024;
    unsigned short* Btf = (unsigned short*)(gfac + 1024);

    hipMemsetAsync(colss, 0, (size_t)(1024 + M) * sizeof(float), stream);  // colss + rowsum
    sumsq_cols<<<128, 256, 0, stream>>>(wv, colss);
    finalize_cols<<<OUT / 256, 256, 0, stream>>>(colss, wg, bias, cptr, colinv, coshd, sinhd, gfac);
    build_bt<<<(IN / 64) * (OUT / 64), 256, 0, stream>>>(wv, colinv, Btf);
    gemm_phase<<<(M / 128) * (OUT / 128), 256, 0, stream>>>(x, Btf, cptr, coshd, sinhd, gfac, out, rowsum);
    rescale<<<M, 256, 0, stream>>>(out, rowsum, cptr);
}

// Round 3
// 397.360 us; speedup vs baseline: 1.1482x; 1.0736x over previous
//
#include <hip/hip_runtime.h>

#define K_DIM 1024
#define N_DIM 1024

typedef short v8s __attribute__((ext_vector_type(8)));
typedef float v4f __attribute__((ext_vector_type(4)));

__device__ __forceinline__ unsigned int bf16_rne(float f) {
    unsigned int u = __float_as_uint(f);
    u += 0x7FFFu + ((u >> 16) & 1u);
    return u >> 16;
}

// ---------- colss[n] += partial sum of wv[:,n]^2 ----------
__global__ void sumsq_cols(const float* __restrict__ wv, float* __restrict__ colss) {
    __shared__ float red[4][64];
    const int t = threadIdx.x;
    const int cj = t & 63, rr = t >> 6;
    const int col = (blockIdx.x & 15) * 64 + cj;
    const int k0 = (blockIdx.x >> 4) * 128 + rr * 32;
    float ss = 0.f;
#pragma unroll 8
    for (int i = 0; i < 32; ++i) {
        float v = wv[(size_t)(k0 + i) * N_DIM + col];
        ss = fmaf(v, v, ss);
    }
    red[rr][cj] = ss;
    __syncthreads();
    if (rr == 0) atomicAdd(&colss[col], red[0][cj] + red[1][cj] + red[2][cj] + red[3][cj]);
}

// ---------- per-column constants ----------
__global__ void finalize_cols(const float* __restrict__ colss, const float* __restrict__ wg,
                              const float* __restrict__ bias, const float* __restrict__ cptr,
                              float* __restrict__ colinv, float* __restrict__ coshd,
                              float* __restrict__ sinhd, float* __restrict__ gfac) {
    const int col = blockIdx.x * 256 + threadIdx.x;
    const float rc = sqrtf(cptr[0]);
    colinv[col] = 1.0f / fmaxf(sqrtf(colss[col]), 1e-15f);
    float d = 2.0f * rc * bias[col];
    float e = __expf(d), ie = 1.0f / e;
    coshd[col] = 0.5f * (e + ie);
    sinhd[col] = 0.5f * (e - ie);
    gfac[col] = 2.0f * wg[col];
}

// ---------- Btf: z_unit^T in MFMA B-fragment order ----------
__global__ void build_bt(const float* __restrict__ wv, const float* __restrict__ colinv,
                         unsigned short* __restrict__ Btf) {
    __shared__ float tile[64 * 65];
    const int t = threadIdx.x;
    const int ti = blockIdx.x & 15;   // k tile of 64
    const int tj = blockIdx.x >> 4;   // n tile of 64
    {
        const int kl = t >> 2;
        const int cc = t & 3;
        const float* src = wv + (size_t)(ti * 64 + kl) * N_DIM + tj * 64 + cc * 16;
        float4 fq[4];
#pragma unroll
        for (int i = 0; i < 4; ++i) fq[i] = ((const float4*)src)[i];
        float* dst = &tile[kl * 65 + cc * 16];
#pragma unroll
        for (int i = 0; i < 4; ++i) {
            dst[4 * i + 0] = fq[i].x; dst[4 * i + 1] = fq[i].y;
            dst[4 * i + 2] = fq[i].z; dst[4 * i + 3] = fq[i].w;
        }
    }
    __syncthreads();
    {
        const int nl = t & 63, kc = t >> 6;
        const int n = tj * 64 + nl;
        const float ci = colinv[n];
        const int nt_g = tj * 4 + (nl >> 4);
#pragma unroll
        for (int h = 0; h < 2; ++h) {
            const int k8g = ti * 8 + kc * 2 + h;
            const int ks_g = k8g >> 2;
            const int L = (nl & 15) | ((k8g & 3) << 4);
            unsigned int p[4];
#pragma unroll
            for (int j = 0; j < 4; ++j) {
                float v0 = tile[(kc * 16 + h * 8 + 2 * j) * 65 + nl] * ci;
                float v1 = tile[(kc * 16 + h * 8 + 2 * j + 1) * 65 + nl] * ci;
                p[j] = bf16_rne(v0) | (bf16_rne(v1) << 16);
            }
            *(uint4*)(Btf + ((size_t)(nt_g * 32 + ks_g) * 64 + L) * 8) =
                make_uint4(p[0], p[1], p[2], p[3]);
        }
    }
}

// ---------- prep_a: x -> bf16 in MFMA A-fragment order + row sumsq ----------
// Axf frag block (mt, ks): lane L holds x[mt*16 + (L&15)][ks*32 + (L>>4)*8 + j]
__global__ void prep_a(const float* __restrict__ x, unsigned short* __restrict__ Axf,
                       float* __restrict__ rowss) {
    __shared__ float xs[16 * 1028];   // stride 1028 floats: 16B-aligned rows, 2-way banks max
    const int t = threadIdx.x;
    const int b = blockIdx.x;         // global mt index, rows b*16..b*16+15
    {
        const int r = t >> 4;         // 0..15
        const int c = t & 15;
        const float* xp = x + (size_t)(b * 16 + r) * K_DIM + c * 4;
        float* dst = &xs[r * 1028 + c * 4];
        float ss = 0.f;
#pragma unroll
        for (int it = 0; it < 16; ++it) {
            float4 v = *(const float4*)(xp + it * 64);
            ss = fmaf(v.x, v.x, ss); ss = fmaf(v.y, v.y, ss);
            ss = fmaf(v.z, v.z, ss); ss = fmaf(v.w, v.w, ss);
            *(float4*)(dst + it * 64) = v;
        }
        ss += __shfl_xor(ss, 1); ss += __shfl_xor(ss, 2);
        ss += __shfl_xor(ss, 4); ss += __shfl_xor(ss, 8);
        if (c == 0) rowss[b * 16 + r] = ss;
    }
    __syncthreads();
    {
        const int w = t >> 6, L = t & 63;
        const int lm = L & 15, q = L >> 4;
#pragma unroll
        for (int i = 0; i < 8; ++i) {
            const int ks = w * 8 + i;
            const float* src = &xs[lm * 1028 + ks * 32 + q * 8];
            float4 f0 = *(const float4*)(src);
            float4 f1 = *(const float4*)(src + 4);
            float vals[8] = {f0.x, f0.y, f0.z, f0.w, f1.x, f1.y, f1.z, f1.w};
            unsigned int p[4];
#pragma unroll
            for (int j = 0; j < 4; ++j)
                p[j] = bf16_rne(vals[2 * j]) | (bf16_rne(vals[2 * j + 1]) << 16);
            *(uint4*)(Axf + ((size_t)b * 32 + ks) * 512 + L * 8) =
                make_uint4(p[0], p[1], p[2], p[3]);
        }
    }
}

// ---------- GEMM via global_load_lds for BOTH A and B + fused epilogue ----------
__launch_bounds__(256, 4)
__global__ void gemm_fast(const unsigned short* __restrict__ Axf,
                          const unsigned short* __restrict__ Btf,
                          const float* __restrict__ rowss, const float* __restrict__ cptr,
                          const float* __restrict__ coshd, const float* __restrict__ sinhd,
                          const float* __restrict__ gfac,
                          float* __restrict__ out, float* __restrict__ rowsum) {
    __shared__ __align__(16) unsigned short As[16 * 512];
    __shared__ __align__(16) unsigned short Bs[16 * 512];
    __shared__ float s_cx2[128];
    __shared__ float s_rsum[128];

    const int t = threadIdx.x;
    const int w = t >> 6, L = t & 63;
    const int lm = L & 15, q = L >> 4;
    const int bn = blockIdx.x & 7;
    const int bm = blockIdx.x >> 3;
    const int r0 = bm * 128;

    if (t < 128) { s_cx2[t] = rowss[r0 + t]; s_rsum[t] = 0.f; }

    v4f acc[16];
#pragma unroll
    for (int i = 0; i < 16; ++i) acc[i] = (v4f){0.f, 0.f, 0.f, 0.f};

    const int mt0 = w * 2;
    const int wm = w & 1, wn = w >> 1;

    for (int kq = 0; kq < 16; ++kq) {
#pragma unroll
        for (int i = 0; i < 4; ++i) {
            const int mtl = mt0 + (i & 1);
            const int ks = i >> 1;
            const unsigned short* gp =
                Axf + ((size_t)((bm * 8 + mtl) * 32) + (kq * 2 + ks)) * 512 + L * 8;
            __builtin_amdgcn_global_load_lds(
                (const __attribute__((address_space(1))) unsigned int*)gp,
                (__attribute__((address_space(3))) unsigned int*)&As[(mtl * 2 + ks) * 512],
                16, 0, 0);
        }
#pragma unroll
        for (int i = 0; i < 4; ++i) {
            const int nt = mt0 + (i & 1);
            const int ks = i >> 1;
            const unsigned short* gp =
                Btf + ((size_t)((bn * 8 + nt) * 32) + (kq * 2 + ks)) * 512 + L * 8;
            __builtin_amdgcn_global_load_lds(
                (const __attribute__((address_space(1))) unsigned int*)gp,
                (__attribute__((address_space(3))) unsigned int*)&Bs[(nt * 2 + ks) * 512],
                16, 0, 0);
        }
        __syncthreads();
#pragma unroll
        for (int ks = 0; ks < 2; ++ks) {
            v8s a[4], b[4];
#pragma unroll
            for (int mi = 0; mi < 4; ++mi)
                a[mi] = *(const v8s*)&As[((wm * 4 + mi) * 2 + ks) * 512 + L * 8];
#pragma unroll
            for (int ni = 0; ni < 4; ++ni)
                b[ni] = *(const v8s*)&Bs[((wn * 4 + ni) * 2 + ks) * 512 + L * 8];
#pragma unroll
            for (int mi = 0; mi < 4; ++mi)
#pragma unroll
                for (int ni = 0; ni < 4; ++ni)
                    acc[mi * 4 + ni] = __builtin_amdgcn_mfma_f32_16x16x32_bf16(
                        a[mi], b[ni], acc[mi * 4 + ni], 0, 0, 0);
        }
        __syncthreads();
    }

    const float cc = cptr[0];
    const float rc = sqrtf(cc);
    const float two_rc = 2.0f * rc;
    const float halfinvrc = 0.5f / rc;
    float ch[4], sh[4], gf[4];
#pragma unroll
    for (int ni = 0; ni < 4; ++ni) {
        const int n = bn * 128 + wn * 64 + ni * 16 + lm;
        ch[ni] = coshd[n]; sh[ni] = sinhd[n]; gf[ni] = gfac[n];
    }
#pragma unroll
    for (int mi = 0; mi < 4; ++mi) {
        const int mloc = wm * 64 + mi * 16 + q * 4;
        float sx[4];
#pragma unroll
        for (int rr = 0; rr < 4; ++rr) sx[rr] = cc * s_cx2[mloc + rr];
        float rs[4] = {0.f, 0.f, 0.f, 0.f};
#pragma unroll
        for (int ni = 0; ni < 4; ++ni) {
            v4f d = acc[mi * 4 + ni];
#pragma unroll
            for (int rr = 0; rr < 4; ++rr) {
                float cx2 = sx[rr];
                float num = two_rc * d[rr] * ch[ni] - (1.0f + cx2) * sh[ni];
                float den = fmaxf(1.0f - cx2, 1e-15f);
                float tt = num * __builtin_amdgcn_rcpf(den);
                float as_ = __logf(fabsf(tt) + sqrtf(fmaf(tt, tt, 1.0f)));
                as_ = copysignf(as_, tt);
                float u = gf[ni] * as_;
                float e = __expf(u);
                float y = (e - __builtin_amdgcn_rcpf(e)) * halfinvrc;
                d[rr] = y;
                rs[rr] = fmaf(y, y, rs[rr]);
            }
            acc[mi * 4 + ni] = d;
        }
#pragma unroll
        for (int rr = 0; rr < 4; ++rr) {
            float v = rs[rr];
            v += __shfl_xor(v, 1); v += __shfl_xor(v, 2);
            v += __shfl_xor(v, 4); v += __shfl_xor(v, 8);
            if (lm == 0) atomicAdd(&s_rsum[mloc + rr], v);
        }
#pragma unroll
        for (int rr = 0; rr < 4; ++rr) {
            const int row = r0 + mloc + rr;
            float* op = out + (size_t)row * N_DIM + bn * 128 + wn * 64 + lm;
#pragma unroll
            for (int ni = 0; ni < 4; ++ni) op[ni * 16] = acc[mi * 4 + ni][rr];
        }
    }
    __syncthreads();
    if (t < 128) atomicAdd(&rowsum[r0 + t], s_rsum[t]);
}

// ---------- fallback GEMM (round-2, fp32 x staged in-kernel) ----------
__launch_bounds__(256, 3)
__global__ void gemm_phase(const float* __restrict__ x, const unsigned short* __restrict__ Btf,
                           const float* __restrict__ cptr, const float* __restrict__ coshd,
                           const float* __restrict__ sinhd, const float* __restrict__ gfac,
                           float* __restrict__ out, float* __restrict__ rowsum) {
    __shared__ __align__(16) unsigned short As[16 * 512];
    __shared__ __align__(16) unsigned short Bs[16 * 512];
    __shared__ float s_cx2[128];
    __shared__ float s_rsum[128];

    const int t = threadIdx.x;
    const int w = t >> 6, L = t & 63;
    const int lm = L & 15, q = L >> 4;
    const int bn = blockIdx.x & 7;
    const int bm = blockIdx.x >> 3;
    const int r0 = bm * 128;

    if (t < 128) { s_cx2[t] = 0.f; s_rsum[t] = 0.f; }

    v4f acc[16];
#pragma unroll
    for (int i = 0; i < 16; ++i) acc[i] = (v4f){0.f, 0.f, 0.f, 0.f};

    const int smt0 = w * 2;
    const float* xr0 = x + (size_t)(r0 + smt0 * 16 + lm) * K_DIM;
    const float* xr1 = xr0 + (size_t)16 * K_DIM;
    float xp0 = 0.f, xp1 = 0.f;
    const int wm = w & 1, wn = w >> 1;

    for (int kq = 0; kq < 16; ++kq) {
        const int kbase = kq * 64;
#pragma unroll
        for (int i = 0; i < 4; ++i) {
            const int nt = smt0 + (i & 1);
            const int ks = i >> 1;
            const unsigned short* gp =
                Btf + ((size_t)((bn * 8 + nt) * 32 + (kq * 2 + ks)) * 64 + L) * 8;
            __builtin_amdgcn_global_load_lds(
                (const __attribute__((address_space(1))) unsigned int*)gp,
                (__attribute__((address_space(3))) unsigned int*)&Bs[(nt * 2 + ks) * 512],
                16, 0, 0);
        }
#pragma unroll
        for (int i = 0; i < 4; ++i) {
            const int half = i & 1;
            const int ks = i >> 1;
            const float* xr = half ? xr1 : xr0;
            const int kg = kbase + ks * 32 + q * 8;
            float4 f0 = *(const float4*)(xr + kg);
            float4 f1 = *(const float4*)(xr + kg + 4);
            float vals[8] = {f0.x, f0.y, f0.z, f0.w, f1.x, f1.y, f1.z, f1.w};
            unsigned int pk[4];
            float ssl = 0.f;
#pragma unroll
            for (int j = 0; j < 4; ++j) {
                ssl = fmaf(vals[2 * j], vals[2 * j], ssl);
                ssl = fmaf(vals[2 * j + 1], vals[2 * j + 1], ssl);
                pk[j] = bf16_rne(vals[2 * j]) | (bf16_rne(vals[2 * j + 1]) << 16);
            }
            if (half) xp1 += ssl; else xp0 += ssl;
            *(uint4*)&As[((smt0 + half) * 2 + ks) * 512 + L * 8] =
                make_uint4(pk[0], pk[1], pk[2], pk[3]);
        }
        __syncthreads();
#pragma unroll
        for (int ks = 0; ks < 2; ++ks) {
            v8s a[4], b[4];
#pragma unroll
            for (int mi = 0; mi < 4; ++mi)
                a[mi] = *(const v8s*)&As[((wm * 4 + mi) * 2 + ks) * 512 + L * 8];
#pragma unroll
            for (int ni = 0; ni < 4; ++ni)
                b[ni] = *(const v8s*)&Bs[((wn * 4 + ni) * 2 + ks) * 512 + L * 8];
#pragma unroll
            for (int mi = 0; mi < 4; ++mi)
#pragma unroll
                for (int ni = 0; ni < 4; ++ni)
                    acc[mi * 4 + ni] = __builtin_amdgcn_mfma_f32_16x16x32_bf16(
                        a[mi], b[ni], acc[mi * 4 + ni], 0, 0, 0);
        }
        __syncthreads();
    }

    atomicAdd(&s_cx2[smt0 * 16 + lm], xp0);
    atomicAdd(&s_cx2[smt0 * 16 + 16 + lm], xp1);
    __syncthreads();

    const float cc = cptr[0];
    const float rc = sqrtf(cc);
    const float two_rc = 2.0f * rc;
    const float halfinvrc = 0.5f / rc;
    float ch[4], sh[4], gf[4];
#pragma unroll
    for (int ni = 0; ni < 4; ++ni) {
        const int n = bn * 128 + wn * 64 + ni * 16 + lm;
        ch[ni] = coshd[n]; sh[ni] = sinhd[n]; gf[ni] = gfac[n];
    }
#pragma unroll
    for (int mi = 0; mi < 4; ++mi) {
        const int mloc = wm * 64 + mi * 16 + q * 4;
        float sx[4];
#pragma unroll
        for (int rr = 0; rr < 4; ++rr) sx[rr] = cc * s_cx2[mloc + rr];
        float rs[4] = {0.f, 0.f, 0.f, 0.f};
#pragma unroll
        for (int ni = 0; ni < 4; ++ni) {
            v4f d = acc[mi * 4 + ni];
#pragma unroll
            for (int rr = 0; rr < 4; ++rr) {
                float cx2 = sx[rr];
                float num = two_rc * d[rr] * ch[ni] - (1.0f + cx2) * sh[ni];
                float den = fmaxf(1.0f - cx2, 1e-15f);
                float tt = num * __builtin_amdgcn_rcpf(den);
                float as_ = __logf(fabsf(tt) + sqrtf(fmaf(tt, tt, 1.0f)));
                as_ = copysignf(as_, tt);
                float u = gf[ni] * as_;
                float e = __expf(u);
                float y = (e - __builtin_amdgcn_rcpf(e)) * halfinvrc;
                d[rr] = y;
                rs[rr] = fmaf(y, y, rs[rr]);
            }
            acc[mi * 4 + ni] = d;
        }
#pragma unroll
        for (int rr = 0; rr < 4; ++rr) {
            float v = rs[rr];
            v += __shfl_xor(v, 1); v += __shfl_xor(v, 2);
            v += __shfl_xor(v, 4); v += __shfl_xor(v, 8);
            if (lm == 0) atomicAdd(&s_rsum[mloc + rr], v);
        }
#pragma unroll
        for (int rr = 0; rr < 4; ++rr) {
            const int row = r0 + mloc + rr;
            float* op = out + (size_t)row * N_DIM + bn * 128 + wn * 64 + lm;
#pragma unroll
            for (int ni = 0; ni < 4; ++ni) op[ni * 16] = acc[mi * 4 + ni][rr];
        }
    }
    __syncthreads();
    if (t < 128) atomicAdd(&rowsum[r0 + t], s_rsum[t]);
}

// ---------- in-place row rescale (4 rows/block) ----------
__global__ void rescale(float* __restrict__ out, const float* __restrict__ rowsum,
                        const float* __restrict__ cptr) {
    const int t = threadIdx.x;
    const int row = blockIdx.x * 4 + (t >> 6);
    const float cc = cptr[0];
    const float s = rowsum[row];
    const float scale = 1.0f / (1.0f + sqrtf(fmaf(cc, s, 1.0f)));
    const float nrm = fmaxf(sqrtf(s) * scale, 1e-15f);
    const float mn = (cc > 0.f) ? 0.996f / sqrtf(fmaxf(cc, 1e-15f)) : 1e15f;
    const float f = scale * (nrm > mn ? mn / nrm : 1.0f);
    float4* p = (float4*)(out + (size_t)row * N_DIM) + (t & 63);
#pragma unroll
    for (int j = 0; j < 4; ++j) {
        float4 v = p[j * 64];
        v.x *= f; v.y *= f; v.z *= f; v.w *= f;
        p[j * 64] = v;
    }
}

extern "C" void kernel_launch(void* const* d_in, const int* in_sizes, int n_in,
                              void* d_out, int out_size, void* d_ws, size_t ws_size,
                              hipStream_t stream) {
    const float* x    = (const float*)d_in[0];
    const float* wv   = (const float*)d_in[1];
    const float* wg   = (const float*)d_in[2];
    const float* bias = (const float*)d_in[3];
    const float* cptr = (const float*)d_in[4];
    float* out = (float*)d_out;

    const int OUT = in_sizes[2];            // 1024
    const int IN  = in_sizes[1] / OUT;      // 1024
    const int M   = in_sizes[0] / IN;       // 32768

    // ws layout: colss[1024] | rowsum[M] | rowss[M] | colinv/coshd/sinhd/gfac[4096] | Btf | Axf
    float* colss  = (float*)d_ws;
    float* rowsum = colss + 1024;
    float* rowss  = rowsum + M;
    float* colinv = rowss + M;
    float* coshd  = colinv + 1024;
    float* sinhd  = coshd + 1024;
    float* gfac   = sinhd + 1024;
    unsigned short* Btf = (unsigned short*)(gfac + 1024);
    unsigned short* Axf = Btf + (size_t)IN * OUT;

    const size_t need = (size_t)(1024 + 2 * M + 4096) * 4 + (size_t)IN * OUT * 2
                      + (size_t)M * IN * 2;

    hipMemsetAsync(rowsum, 0, (size_t)M * sizeof(float), stream);
    hipMemsetAsync(colss, 0, 1024 * sizeof(float), stream);
    sumsq_cols<<<128, 256, 0, stream>>>(wv, colss);
    finalize_cols<<<OUT / 256, 256, 0, stream>>>(colss, wg, bias, cptr, colinv, coshd, sinhd, gfac);
    build_bt<<<(IN / 64) * (OUT / 64), 256, 0, stream>>>(wv, colinv, Btf);
    if (ws_size >= need) {
        prep_a<<<M / 16, 256, 0, stream>>>(x, Axf, rowss);
        gemm_fast<<<(M / 128) * (OUT / 128), 256, 0, stream>>>(
            Axf, Btf, rowss, cptr, coshd, sinhd, gfac, out, rowsum);
    } else {
        gemm_phase<<<(M / 128) * (OUT / 128), 256, 0, stream>>>(
            x, Btf, cptr, coshd, sinhd, gfac, out, rowsum);
    }
    rescale<<<M / 4, 256, 0, stream>>>(out, rowsum, cptr);
}